// Round 1
// baseline (2729.296 us; speedup 1.0000x reference)
//
#include <hip/hip_runtime.h>
#include <hip/hip_bf16.h>

#define T_N 50000
#define N_N 5000
#define E_N 800000
#define FIN 4652
#define KP1 4672     // FIN padded to multiple of 32
#define DIM 256

typedef __bf16 bf16;
typedef __bf16 bf16x8 __attribute__((ext_vector_type(8)));
typedef float f32x4 __attribute__((ext_vector_type(4)));
typedef unsigned int u32;
typedef __attribute__((address_space(1))) const u32 gu32;
typedef __attribute__((address_space(3))) u32 lu32;

// ---------------- weight prep: W[K][256] fp32 -> Wt[256][Kpad] bf16 (zero-pad K tail)
__global__ void prep_w_k(const float* __restrict__ W, bf16* __restrict__ Wt,
                         int K, int Kpad) {
  int k = blockIdx.x;      // [0, Kpad)
  int n = threadIdx.x;     // [0, 256)
  float v = (k < K) ? W[(size_t)k * DIM + n] : 0.f;
  Wt[(size_t)n * Kpad + k] = (bf16)v;
}

// ---------------- histogram / dinv / scan / scatter (counting sort by bin)
__global__ void hist_k(const int* __restrict__ bins, int* __restrict__ cnt, int n) {
  int i = blockIdx.x * 256 + threadIdx.x;
  if (i < n) atomicAdd(&cnt[bins[i]], 1);
}

__global__ void dinv_k(const int* __restrict__ cnt, float* __restrict__ dinv, int n) {
  int i = blockIdx.x * 256 + threadIdx.x;
  if (i < n) dinv[i] = rsqrtf((float)(cnt[i] + 1));   // +1 self-loop; always >0
}

// single-block exclusive scan; writes offsets and a cursor copy for the scatter
__global__ void scan_k(const int* __restrict__ cnt, int* __restrict__ offs,
                       int* __restrict__ curs, int n) {
  __shared__ int wsum[16];
  __shared__ int carry_s;
  int tid = threadIdx.x, wv = tid >> 6, ln = tid & 63;
  if (tid == 0) carry_s = 0;
  __syncthreads();
  for (int base = 0; base < n; base += 1024) {
    int i = base + tid;
    int v = (i < n) ? cnt[i] : 0;
    int s = v;                                  // inclusive wave scan
#pragma unroll
    for (int off = 1; off < 64; off <<= 1) {
      int t = __shfl_up(s, off);
      if (ln >= off) s += t;
    }
    if (ln == 63) wsum[wv] = s;
    __syncthreads();
    if (wv == 0) {                              // scan the 16 wave sums
      int w = (ln < 16) ? wsum[ln] : 0;
#pragma unroll
      for (int off = 1; off < 16; off <<= 1) {
        int t = __shfl_up(w, off);
        if (ln >= off) w += t;
      }
      if (ln < 16) wsum[ln] = w;
    }
    __syncthreads();
    int woff = (wv == 0) ? 0 : wsum[wv - 1];
    int total = wsum[15];
    int excl = carry_s + woff + (s - v);
    if (i < n) { offs[i] = excl; curs[i] = excl; }
    __syncthreads();                            // everyone has read carry_s/total
    if (tid == 0) carry_s += total;
    __syncthreads();
  }
}

// place item payload (or its own index) into its bin's segment
__global__ void scatter_k(const int* __restrict__ bins, const int* __restrict__ payload,
                          int* __restrict__ curs, int* __restrict__ out, int n) {
  int i = blockIdx.x * 256 + threadIdx.x;
  if (i < n) {
    int p = atomicAdd(&curs[bins[i]], 1);
    out[p] = payload ? payload[i] : i;
  }
}

// ---------------- GCN edge aggregation (sorted-by-dst, no float atomics)
// 8 groups x 32 lanes: 8 edges in flight, bf16x8 (16B/lane) row loads, LDS reduce.
__global__ __launch_bounds__(256) void gcn_agg_k(
    const bf16* __restrict__ P, const int* __restrict__ offs,
    const int* __restrict__ cnt, const int* __restrict__ ssrc,
    const float* __restrict__ dinv, const float* __restrict__ bias,
    bf16* __restrict__ HC, int col_off) {
  __shared__ float red[8][256];
  int i = blockIdx.x;
  int tid = threadIdx.x, g = tid >> 5, l = tid & 31;
  float di = dinv[i];
  float acc[8];
#pragma unroll
  for (int j = 0; j < 8; j++) acc[j] = 0.f;
  if (g == 0) {                                  // self-loop term
    bf16x8 v = *(const bf16x8*)(P + (size_t)i * DIM + l * 8);
    float w = di * di;
#pragma unroll
    for (int j = 0; j < 8; j++) acc[j] += (float)v[j] * w;
  }
  int s0 = offs[i], e1 = s0 + cnt[i];
  for (int e = s0 + g; e < e1; e += 8) {
    int s = ssrc[e];
    float w = dinv[s] * di;
    bf16x8 v = *(const bf16x8*)(P + (size_t)s * DIM + l * 8);
#pragma unroll
    for (int j = 0; j < 8; j++) acc[j] += (float)v[j] * w;
  }
#pragma unroll
  for (int j = 0; j < 8; j++) red[g][l * 8 + j] = acc[j];
  __syncthreads();
  float r = 0.f;
#pragma unroll
  for (int gg = 0; gg < 8; gg++) r += red[gg][tid];
  float v = r + bias[tid];
  HC[(size_t)i * 512 + col_off + tid] = (bf16)fmaxf(v, 0.f);
}

// ---------------- scatter-mean into RC[n, col_off + d] (same 8-group structure)
__global__ __launch_bounds__(256) void mean_agg_k(
    const bf16* __restrict__ Hf, const int* __restrict__ offs,
    const int* __restrict__ cnt, const int* __restrict__ ids,
    bf16* __restrict__ RC, int col_off) {
  __shared__ float red[8][256];
  int nb = blockIdx.x;
  int tid = threadIdx.x, g = tid >> 5, l = tid & 31;
  int s0 = offs[nb], c = cnt[nb];
  float acc[8];
#pragma unroll
  for (int j = 0; j < 8; j++) acc[j] = 0.f;
  for (int e = s0 + g; e < s0 + c; e += 8) {
    int t = ids[e];
    bf16x8 v = *(const bf16x8*)(Hf + (size_t)t * DIM + l * 8);
#pragma unroll
    for (int j = 0; j < 8; j++) acc[j] += (float)v[j];
  }
#pragma unroll
  for (int j = 0; j < 8; j++) red[g][l * 8 + j] = acc[j];
  __syncthreads();
  float r = 0.f;
#pragma unroll
  for (int gg = 0; gg < 8; gg++) r += red[gg][tid];
  float denom = (c > 0) ? (float)c : 1.f;
  RC[(size_t)nb * 512 + col_off + tid] = (bf16)(r / denom);
}

// ---------------- skinny MFMA GEMM, whole-K A-tile in LDS, barrier-free K-loop.
// A bf16 [M,K] row-major (ws buffer: OOB tail rows stay inside ws), Wt bf16 [256][K],
// C bf16 [M,256]. A staged via global_load_lds w/ XOR-swizzled source (linear LDS dest);
// B fragments read directly from L2-hot Wt (staging had zero intra-block reuse).
template <int K>
__global__ __launch_bounds__(256) void gemm_b_k(
    const bf16* __restrict__ A, const bf16* __restrict__ Wt,
    const float* __restrict__ bias, bf16* __restrict__ C,
    int M, int relu) {
  constexpr int RB = K * 2;                  // bytes per row
  constexpr int RSH = (K == 256) ? 9 : 10;   // log2(RB)
  constexpr int NC = (64 * RB) / 1024;       // 1 KiB staging chunks
  __shared__ __align__(16) char As[64 * RB];
  int tid = threadIdx.x;
  int wv = tid >> 6, ln = tid & 63;
  int q = ln >> 4, r16 = ln & 15;
  int bm = blockIdx.x * 64;
  const char* Ab = (const char*)(A + (size_t)bm * K);
  for (int c = wv; c < NC; c += 4) {
    int lo = c * 1024;                       // wave-uniform LDS dest
    int t = lo + ln * 16;                    // linear tile byte this lane covers
    int row = t >> RSH;
    int src = t ^ ((row & 7) << 4);          // inverse-swizzle the SOURCE (m173)
    __builtin_amdgcn_global_load_lds((gu32*)(Ab + src), (lu32*)(As + lo), 16, 0, 0);
  }
  __syncthreads();                           // only barrier in the kernel body

  const bf16* Bp = Wt + (size_t)(wv * 64 + r16) * K + q * 8;
  f32x4 acc[4][4];
#pragma unroll
  for (int i = 0; i < 4; i++)
#pragma unroll
    for (int j = 0; j < 4; j++) acc[i][j] = f32x4{0.f, 0.f, 0.f, 0.f};

  int abase[4], axor[4];
#pragma unroll
  for (int mi = 0; mi < 4; mi++) {
    int row = mi * 16 + r16;
    abase[mi] = row * RB + q * 16;
    axor[mi] = (row & 7) << 4;
  }
#pragma unroll 2
  for (int k0 = 0; k0 < K; k0 += 32) {
    bf16x8 af[4], bv[4];
#pragma unroll
    for (int mi = 0; mi < 4; mi++)
      af[mi] = *(const bf16x8*)(As + ((abase[mi] + k0 * 2) ^ axor[mi]));
#pragma unroll
    for (int ni = 0; ni < 4; ni++)
      bv[ni] = *(const bf16x8*)(Bp + (size_t)ni * 16 * K + k0);
#pragma unroll
    for (int mi = 0; mi < 4; mi++)
#pragma unroll
      for (int ni = 0; ni < 4; ni++)
        acc[mi][ni] = __builtin_amdgcn_mfma_f32_16x16x32_bf16(af[mi], bv[ni], acc[mi][ni], 0, 0, 0);
  }
#pragma unroll
  for (int ni = 0; ni < 4; ni++) {
    int ng = wv * 64 + ni * 16 + r16;
    float bvv = bias ? bias[ng] : 0.f;
#pragma unroll
    for (int mi = 0; mi < 4; mi++) {
#pragma unroll
      for (int rr = 0; rr < 4; rr++) {
        int mg = bm + mi * 16 + q * 4 + rr;
        if (mg < M) {
          float vv = acc[mi][ni][rr] + bvv;
          if (relu) vv = fmaxf(vv, 0.f);
          C[(size_t)mg * DIM + ng] = (bf16)vv;
        }
      }
    }
  }
}

// ---------------- GEMM1: A = x fp32 [50000,4652] cvt->bf16, double-buffered As,
// one barrier per K-step, B direct from L2 (WtI1 is 2.4 MB, L2-resident).
#define LDA 40   // LDS row pad (elements) to spread banks

__device__ __forceinline__ void load_x8(const float* __restrict__ Xp, int kg, float* f) {
  if (kg + 8 <= FIN) {
    float4 u0 = *(const float4*)(Xp + kg);
    float4 u1 = *(const float4*)(Xp + kg + 4);
    f[0] = u0.x; f[1] = u0.y; f[2] = u0.z; f[3] = u0.w;
    f[4] = u1.x; f[5] = u1.y; f[6] = u1.z; f[7] = u1.w;
  } else {
#pragma unroll
    for (int j = 0; j < 8; j++) f[j] = (kg + j < FIN) ? Xp[kg + j] : 0.f;
  }
}

__global__ __launch_bounds__(256) void gemm_x_k(
    const float* __restrict__ X, const bf16* __restrict__ Wt,
    const float* __restrict__ bias, bf16* __restrict__ C) {
  __shared__ __align__(16) bf16 As[2][64 * LDA];
  int tid = threadIdx.x;
  int wv = tid >> 6, ln = tid & 63;
  int q = ln >> 4, r16 = ln & 15;
  int bm = blockIdx.x * 64;
  int ar = tid >> 2, acol = (tid & 3) * 8;      // 8 fp32/thread per step
  int arow = bm + ar; if (arow > T_N - 1) arow = T_N - 1;   // X is an input: clamp
  const float* Xp = X + (size_t)arow * FIN;
  const bf16* Bp = Wt + (size_t)(wv * 64 + r16) * KP1 + q * 8;
  f32x4 acc[4][4];
#pragma unroll
  for (int i = 0; i < 4; i++)
#pragma unroll
    for (int j = 0; j < 4; j++) acc[i][j] = f32x4{0.f, 0.f, 0.f, 0.f};

  {                                             // prologue: stage tile 0
    float f0[8];
    load_x8(Xp, acol, f0);
    bf16x8 av;
#pragma unroll
    for (int j = 0; j < 8; j++) av[j] = (bf16)f0[j];
    *(bf16x8*)&As[0][ar * LDA + acol] = av;
  }
  __syncthreads();
  int cur = 0;
  for (int k0 = 0; k0 < KP1; k0 += 32) {
    float fn[8];
    int have = (k0 + 32 < KP1);
    if (have) load_x8(Xp, k0 + 32 + acol, fn);  // issue next-tile loads early
    bf16x8 af[4], bv[4];
#pragma unroll
    for (int mi = 0; mi < 4; mi++)
      af[mi] = *(const bf16x8*)&As[cur][(mi * 16 + r16) * LDA + q * 8];
#pragma unroll
    for (int ni = 0; ni < 4; ni++)
      bv[ni] = *(const bf16x8*)(Bp + (size_t)ni * 16 * KP1 + k0);
#pragma unroll
    for (int mi = 0; mi < 4; mi++)
#pragma unroll
      for (int ni = 0; ni < 4; ni++)
        acc[mi][ni] = __builtin_amdgcn_mfma_f32_16x16x32_bf16(af[mi], bv[ni], acc[mi][ni], 0, 0, 0);
    if (have) {
      bf16x8 av;
#pragma unroll
      for (int j = 0; j < 8; j++) av[j] = (bf16)fn[j];
      *(bf16x8*)&As[cur ^ 1][ar * LDA + acol] = av;   // write the OTHER buffer
    }
    __syncthreads();                             // single barrier per step
    cur ^= 1;
  }
#pragma unroll
  for (int ni = 0; ni < 4; ni++) {
    int ng = wv * 64 + ni * 16 + r16;
    float bv2 = bias[ng];
#pragma unroll
    for (int mi = 0; mi < 4; mi++) {
#pragma unroll
      for (int rr = 0; rr < 4; rr++) {
        int mg = bm + mi * 16 + q * 4 + rr;
        if (mg < T_N) {
          float v = fmaxf(acc[mi][ni][rr] + bv2, 0.f);   // relu
          C[(size_t)mg * DIM + ng] = (bf16)v;
        }
      }
    }
  }
}

// ---------------- head: logits = F1 @ Wfb + bfb; log_softmax. one wave per row
__global__ void final_k(const bf16* __restrict__ F1, const float* __restrict__ Wfb,
                        const float* __restrict__ bfb, float* __restrict__ out) {
  int i = blockIdx.x, l = threadIdx.x;   // 64 threads
  float p[5] = {0.f, 0.f, 0.f, 0.f, 0.f};
  for (int k = l; k < DIM; k += 64) {
    float v = (float)F1[(size_t)i * DIM + k];
#pragma unroll
    for (int c = 0; c < 5; c++) p[c] += v * Wfb[k * 5 + c];
  }
#pragma unroll
  for (int off = 32; off > 0; off >>= 1)
#pragma unroll
    for (int c = 0; c < 5; c++) p[c] += __shfl_down(p[c], off);
  if (l == 0) {
    float z[5], m = -1e30f;
#pragma unroll
    for (int c = 0; c < 5; c++) { z[c] = p[c] + bfb[c]; m = fmaxf(m, z[c]); }
    float s = 0.f;
#pragma unroll
    for (int c = 0; c < 5; c++) s += expf(z[c] - m);
    float ls = m + logf(s);
#pragma unroll
    for (int c = 0; c < 5; c++) out[(size_t)i * 5 + c] = z[c] - ls;
  }
}

extern "C" void kernel_launch(void* const* d_in, const int* in_sizes, int n_in,
                              void* d_out, int out_size, void* d_ws, size_t ws_size,
                              hipStream_t stream) {
  (void)in_sizes; (void)out_size; (void)ws_size;
  if (n_in < 29) return;
  const float* x    = (const float*)d_in[0];
  const int* ei1    = (const int*)d_in[1];
  const int* ei2    = (const int*)d_in[2];
  const int* idx1   = (const int*)d_in[3];
  const int* idx2   = (const int*)d_in[4];
  const float* W_i1 = (const float*)d_in[5];  const float* b_i1 = (const float*)d_in[6];
  const float* W_i2 = (const float*)d_in[7];  const float* b_i2 = (const float*)d_in[8];
  const float* Wc11 = (const float*)d_in[9];  const float* bc11 = (const float*)d_in[10];
  const float* Wc12 = (const float*)d_in[11]; const float* bc12 = (const float*)d_in[12];
  const float* Wc21 = (const float*)d_in[13]; const float* bc21 = (const float*)d_in[14];
  const float* Wc22 = (const float*)d_in[15]; const float* bc22 = (const float*)d_in[16];
  const float* Wm1a = (const float*)d_in[17]; const float* bm1a = (const float*)d_in[18];
  const float* Wm1b = (const float*)d_in[19]; const float* bm1b = (const float*)d_in[20];
  const float* Wm2a = (const float*)d_in[21]; const float* bm2a = (const float*)d_in[22];
  const float* Wm2b = (const float*)d_in[23]; const float* bm2b = (const float*)d_in[24];
  const float* Wfa  = (const float*)d_in[25]; const float* bfa  = (const float*)d_in[26];
  const float* Wfb  = (const float*)d_in[27]; const float* bfb  = (const float*)d_in[28];

  char* base = (char*)d_ws;
  size_t off = 0;
  auto alloc = [&](size_t bytes) -> void* {
    off = (off + 255) & ~(size_t)255;
    void* p = base + off;
    off += bytes;
    return p;
  };

  bf16* WtI1  = (bf16*)alloc((size_t)DIM * KP1 * 2);
  bf16* WtI2  = (bf16*)alloc((size_t)DIM * 256 * 2);
  bf16* WtC11 = (bf16*)alloc((size_t)DIM * 256 * 2);
  bf16* WtC12 = (bf16*)alloc((size_t)DIM * 256 * 2);
  bf16* WtC21 = (bf16*)alloc((size_t)DIM * 256 * 2);
  bf16* WtC22 = (bf16*)alloc((size_t)DIM * 256 * 2);
  bf16* WtM1a = (bf16*)alloc((size_t)DIM * 512 * 2);
  bf16* WtM1b = (bf16*)alloc((size_t)DIM * 256 * 2);
  bf16* WtM2a = (bf16*)alloc((size_t)DIM * 512 * 2);
  bf16* WtM2b = (bf16*)alloc((size_t)DIM * 256 * 2);
  bf16* WtFa  = (bf16*)alloc((size_t)DIM * 512 * 2);

  int* cnt1   = (int*)alloc((size_t)T_N * 4);   // contiguous count region (memset)
  int* cnt2   = (int*)alloc((size_t)T_N * 4);
  int* cntN1  = (int*)alloc((size_t)N_N * 4);
  int* cntN2  = (int*)alloc((size_t)N_N * 4);
  int* offs1  = (int*)alloc((size_t)T_N * 4);
  int* curs1  = (int*)alloc((size_t)T_N * 4);
  int* offs2  = (int*)alloc((size_t)T_N * 4);
  int* curs2  = (int*)alloc((size_t)T_N * 4);
  int* offsN1 = (int*)alloc((size_t)N_N * 4);
  int* cursN1 = (int*)alloc((size_t)N_N * 4);
  int* offsN2 = (int*)alloc((size_t)N_N * 4);
  int* cursN2 = (int*)alloc((size_t)N_N * 4);
  float* dinv1 = (float*)alloc((size_t)T_N * 4);
  float* dinv2 = (float*)alloc((size_t)T_N * 4);
  int* sorted1 = (int*)alloc((size_t)E_N * 4);
  int* sorted2 = (int*)alloc((size_t)E_N * 4);
  int* sortedN1 = (int*)alloc((size_t)T_N * 4);
  int* sortedN2 = (int*)alloc((size_t)T_N * 4);
  bf16* SB0 = (bf16*)alloc((size_t)T_N * DIM * 2);   // 25.6 MB
  bf16* SB1 = (bf16*)alloc((size_t)T_N * DIM * 2);   // 25.6 MB
  bf16* SB2 = (bf16*)alloc((size_t)T_N * 512 * 2);   // 51.2 MB (concat buffer)
  bf16* RC  = (bf16*)alloc((size_t)N_N * 512 * 2);
  bf16* F1  = (bf16*)alloc((size_t)N_N * DIM * 2);
  float* out = (float*)d_out;

  // zero the count arrays (ws is poisoned 0xAA before every call)
  hipMemsetAsync(cnt1, 0, (size_t)((char*)cntN2 + (size_t)N_N * 4 - (char*)cnt1), stream);

  // weight prep (transpose + bf16 convert, pad K for i1)
  prep_w_k<<<KP1, 256, 0, stream>>>(W_i1, WtI1, FIN, KP1);
  prep_w_k<<<256, 256, 0, stream>>>(W_i2, WtI2, 256, 256);
  prep_w_k<<<256, 256, 0, stream>>>(Wc11, WtC11, 256, 256);
  prep_w_k<<<256, 256, 0, stream>>>(Wc12, WtC12, 256, 256);
  prep_w_k<<<256, 256, 0, stream>>>(Wc21, WtC21, 256, 256);
  prep_w_k<<<256, 256, 0, stream>>>(Wc22, WtC22, 256, 256);
  prep_w_k<<<512, 256, 0, stream>>>(Wm1a, WtM1a, 512, 512);
  prep_w_k<<<256, 256, 0, stream>>>(Wm1b, WtM1b, 256, 256);
  prep_w_k<<<512, 256, 0, stream>>>(Wm2a, WtM2a, 512, 512);
  prep_w_k<<<256, 256, 0, stream>>>(Wm2b, WtM2b, 256, 256);
  prep_w_k<<<512, 256, 0, stream>>>(Wfa, WtFa, 512, 512);

  // graph preprocessing: counting sort edges by dst, tuples by node index
  const int GE = (E_N + 255) / 256, GT = (T_N + 255) / 256;
  hist_k<<<GE, 256, 0, stream>>>(ei1 + E_N, cnt1, E_N);   // dst row
  hist_k<<<GE, 256, 0, stream>>>(ei2 + E_N, cnt2, E_N);
  hist_k<<<GT, 256, 0, stream>>>(idx1, cntN1, T_N);
  hist_k<<<GT, 256, 0, stream>>>(idx2, cntN2, T_N);
  dinv_k<<<GT, 256, 0, stream>>>(cnt1, dinv1, T_N);
  dinv_k<<<GT, 256, 0, stream>>>(cnt2, dinv2, T_N);
  scan_k<<<1, 1024, 0, stream>>>(cnt1, offs1, curs1, T_N);
  scan_k<<<1, 1024, 0, stream>>>(cnt2, offs2, curs2, T_N);
  scan_k<<<1, 1024, 0, stream>>>(cntN1, offsN1, cursN1, N_N);
  scan_k<<<1, 1024, 0, stream>>>(cntN2, offsN2, cursN2, N_N);
  scatter_k<<<GE, 256, 0, stream>>>(ei1 + E_N, ei1, curs1, sorted1, E_N);
  scatter_k<<<GE, 256, 0, stream>>>(ei2 + E_N, ei2, curs2, sorted2, E_N);
  scatter_k<<<GT, 256, 0, stream>>>(idx1, nullptr, cursN1, sortedN1, T_N);
  scatter_k<<<GT, 256, 0, stream>>>(idx2, nullptr, cursN2, sortedN2, T_N);

  // network
  const int GM = (T_N + 63) / 64;    // 782
  const int GMn = (N_N + 63) / 64;   // 79
  gemm_x_k<<<GM, 256, 0, stream>>>(x, WtI1, b_i1, SB0);                          // A1=relu(x@Wi1+b)
  gemm_b_k<256><<<GM, 256, 0, stream>>>(SB0, WtI2, b_i2, SB1, T_N, 0);           // H=A1@Wi2+b
  gemm_b_k<256><<<GM, 256, 0, stream>>>(SB1, WtC11, nullptr, SB0, T_N, 0);       // P=H@Wc11
  gcn_agg_k<<<T_N, 256, 0, stream>>>(SB0, offs1, cnt1, sorted1, dinv1, bc11, SB2, 0);
  gemm_b_k<256><<<GM, 256, 0, stream>>>(SB1, WtC12, nullptr, SB0, T_N, 0);       // P=H@Wc12
  gcn_agg_k<<<T_N, 256, 0, stream>>>(SB0, offs2, cnt2, sorted2, dinv2, bc12, SB2, 256);
  gemm_b_k<512><<<GM, 256, 0, stream>>>(SB2, WtM1a, bm1a, SB1, T_N, 1);          // A2=relu(HC@Wm1a+b)
  gemm_b_k<256><<<GM, 256, 0, stream>>>(SB1, WtM1b, bm1b, SB0, T_N, 0);          // H'=A2@Wm1b+b
  gemm_b_k<256><<<GM, 256, 0, stream>>>(SB0, WtC21, nullptr, SB1, T_N, 0);       // P=H'@Wc21
  gcn_agg_k<<<T_N, 256, 0, stream>>>(SB1, offs1, cnt1, sorted1, dinv1, bc21, SB2, 0);
  gemm_b_k<256><<<GM, 256, 0, stream>>>(SB0, WtC22, nullptr, SB1, T_N, 0);       // P=H'@Wc22
  gcn_agg_k<<<T_N, 256, 0, stream>>>(SB1, offs2, cnt2, sorted2, dinv2, bc22, SB2, 256);
  gemm_b_k<512><<<GM, 256, 0, stream>>>(SB2, WtM2a, bm2a, SB0, T_N, 1);          // A3=relu(HC@Wm2a+b)
  gemm_b_k<256><<<GM, 256, 0, stream>>>(SB0, WtM2b, bm2b, SB1, T_N, 0);          // Hf=A3@Wm2b+b
  mean_agg_k<<<N_N, 256, 0, stream>>>(SB1, offsN1, cntN1, sortedN1, RC, 0);      // r1
  mean_agg_k<<<N_N, 256, 0, stream>>>(SB1, offsN2, cntN2, sortedN2, RC, 256);    // r2
  gemm_b_k<512><<<GMn, 256, 0, stream>>>(RC, WtFa, bfa, F1, N_N, 1);             // relu(RC@Wfa+b)
  final_k<<<N_N, 64, 0, stream>>>(F1, Wfb, bfb, out);                            // logits + log_softmax
}

// Round 2
// 2604.176 us; speedup vs baseline: 1.0480x; 1.0480x over previous
//
#include <hip/hip_runtime.h>
#include <hip/hip_bf16.h>

#define T_N 50000
#define N_N 5000
#define E_N 800000
#define FIN 4652
#define KP1 4672     // FIN padded to multiple of 32
#define DIM 256

typedef __bf16 bf16;
typedef __bf16 bf16x8 __attribute__((ext_vector_type(8)));
typedef float f32x4 __attribute__((ext_vector_type(4)));
typedef unsigned int u32;
typedef __attribute__((address_space(1))) const u32 gu32;
typedef __attribute__((address_space(3))) u32 lu32;

// ---------------- fused weight prep: all 11 weights in one kernel.
// W[K][256] fp32 -> Wt[256][Kpad] bf16 (zero-pad K tail); dst may be row-offset
// to pack two weights into one [512][K] buffer (C11|C12, C21|C22).
struct PrepDesc {
  const float* src[11];
  bf16* dst[11];
  int K[11];
  int off[12];   // cumulative Kpad
};

__global__ void prep_all_k(PrepDesc d) {
  int b = blockIdx.x, n = threadIdx.x;   // n in [0,256)
  int e = 0;
  while (b >= d.off[e + 1]) e++;         // wave-uniform linear search (11 entries)
  int k = b - d.off[e];
  int Kp = d.off[e + 1] - d.off[e];
  float v = (k < d.K[e]) ? d.src[e][(size_t)k * DIM + n] : 0.f;
  d.dst[e][(size_t)n * Kp + k] = (bf16)v;
}

// ---------------- fused histogram over both edge relations + both tuple indices
__global__ void hist_all_k(const int* __restrict__ ei1, const int* __restrict__ ei2,
                           const int* __restrict__ idx1, const int* __restrict__ idx2,
                           int* __restrict__ cnt1, int* __restrict__ cnt2,
                           int* __restrict__ cntN1, int* __restrict__ cntN2) {
  int j = blockIdx.x * 256 + threadIdx.x;
  if (j < E_N)                    atomicAdd(&cnt1[ei1[E_N + j]], 1);
  else if (j < 2 * E_N)           atomicAdd(&cnt2[ei2[E_N + (j - E_N)]], 1);
  else if (j < 2 * E_N + T_N)     atomicAdd(&cntN1[idx1[j - 2 * E_N]], 1);
  else if (j < 2 * E_N + 2 * T_N) atomicAdd(&cntN2[idx2[j - 2 * E_N - T_N]], 1);
}

// ---------------- 4 independent single-block scans in one kernel (block = array);
// blocks 0/1 also emit dinv = rsqrt(cnt+1) (self-loop degree) for free.
__global__ __launch_bounds__(1024) void scan4_k(
    const int* __restrict__ c0, const int* __restrict__ c1,
    const int* __restrict__ c2, const int* __restrict__ c3,
    int* __restrict__ o0, int* __restrict__ o1, int* __restrict__ o2, int* __restrict__ o3,
    int* __restrict__ u0, int* __restrict__ u1, int* __restrict__ u2, int* __restrict__ u3,
    float* __restrict__ dv0, float* __restrict__ dv1) {
  __shared__ int wsum[16];
  __shared__ int carry_s;
  int b = blockIdx.x;
  const int* cnt = (b == 0) ? c0 : (b == 1) ? c1 : (b == 2) ? c2 : c3;
  int* offs = (b == 0) ? o0 : (b == 1) ? o1 : (b == 2) ? o2 : o3;
  int* curs = (b == 0) ? u0 : (b == 1) ? u1 : (b == 2) ? u2 : u3;
  float* dv = (b == 0) ? dv0 : (b == 1) ? dv1 : nullptr;
  int n = (b < 2) ? T_N : N_N;
  int tid = threadIdx.x, wv = tid >> 6, ln = tid & 63;
  if (tid == 0) carry_s = 0;
  __syncthreads();
  for (int base = 0; base < n; base += 1024) {
    int i = base + tid;
    int v = (i < n) ? cnt[i] : 0;
    if (dv && i < n) dv[i] = rsqrtf((float)(v + 1));
    int s = v;                                  // inclusive wave scan
#pragma unroll
    for (int off = 1; off < 64; off <<= 1) {
      int t = __shfl_up(s, off);
      if (ln >= off) s += t;
    }
    if (ln == 63) wsum[wv] = s;
    __syncthreads();
    if (wv == 0) {                              // scan the 16 wave sums
      int w = (ln < 16) ? wsum[ln] : 0;
#pragma unroll
      for (int off = 1; off < 16; off <<= 1) {
        int t = __shfl_up(w, off);
        if (ln >= off) w += t;
      }
      if (ln < 16) wsum[ln] = w;
    }
    __syncthreads();
    int woff = (wv == 0) ? 0 : wsum[wv - 1];
    int total = wsum[15];
    int excl = carry_s + woff + (s - v);
    if (i < n) { offs[i] = excl; curs[i] = excl; }
    __syncthreads();                            // everyone has read carry_s/total
    if (tid == 0) carry_s += total;
    __syncthreads();
  }
}

// ---------------- fused counting-sort scatter (both relations + both indices)
__global__ void scatter_all_k(const int* __restrict__ ei1, const int* __restrict__ ei2,
                              const int* __restrict__ idx1, const int* __restrict__ idx2,
                              int* __restrict__ u1, int* __restrict__ u2,
                              int* __restrict__ uN1, int* __restrict__ uN2,
                              int* __restrict__ s1, int* __restrict__ s2,
                              int* __restrict__ sN1, int* __restrict__ sN2) {
  int j = blockIdx.x * 256 + threadIdx.x;
  if (j < E_N) {
    int p = atomicAdd(&u1[ei1[E_N + j]], 1); s1[p] = ei1[j];
  } else if (j < 2 * E_N) {
    int jj = j - E_N;
    int p = atomicAdd(&u2[ei2[E_N + jj]], 1); s2[p] = ei2[jj];
  } else if (j < 2 * E_N + T_N) {
    int t = j - 2 * E_N;
    int p = atomicAdd(&uN1[idx1[t]], 1); sN1[p] = t;
  } else if (j < 2 * E_N + 2 * T_N) {
    int t = j - 2 * E_N - T_N;
    int p = atomicAdd(&uN2[idx2[t]], 1); sN2[p] = t;
  }
}

// ---------------- fused GCN aggregation, BOTH branches (gridDim.y=2).
// P12 [T,512]: branch y occupies cols y*256..y*256+255. 8 groups x 32 lanes,
// bf16x8 row gathers, LDS reduce. HC[i, y*256+d] = relu(bias + norm-agg).
__global__ __launch_bounds__(256) void gcn2_k(
    const bf16* __restrict__ P12,
    const int* __restrict__ offsA, const int* __restrict__ cntA,
    const int* __restrict__ srcA, const float* __restrict__ dinvA,
    const float* __restrict__ biasA,
    const int* __restrict__ offsB, const int* __restrict__ cntB,
    const int* __restrict__ srcB, const float* __restrict__ dinvB,
    const float* __restrict__ biasB,
    bf16* __restrict__ HC) {
  __shared__ float red[8][256];
  int y = blockIdx.y;
  const int* offs = y ? offsB : offsA;
  const int* cnt  = y ? cntB  : cntA;
  const int* ssrc = y ? srcB  : srcA;
  const float* dinv = y ? dinvB : dinvA;
  const float* bias = y ? biasB : biasA;
  int i = blockIdx.x;
  int tid = threadIdx.x, g = tid >> 5, l = tid & 31;
  float di = dinv[i];
  float acc[8];
#pragma unroll
  for (int j = 0; j < 8; j++) acc[j] = 0.f;
  if (g == 0) {                                  // self-loop term
    bf16x8 v = *(const bf16x8*)(P12 + (size_t)i * 512 + y * 256 + l * 8);
    float w = di * di;
#pragma unroll
    for (int j = 0; j < 8; j++) acc[j] += (float)v[j] * w;
  }
  int s0 = offs[i], e1 = s0 + cnt[i];
  for (int e = s0 + g; e < e1; e += 8) {
    int s = ssrc[e];
    float w = dinv[s] * di;
    bf16x8 v = *(const bf16x8*)(P12 + (size_t)s * 512 + y * 256 + l * 8);
#pragma unroll
    for (int j = 0; j < 8; j++) acc[j] += (float)v[j] * w;
  }
#pragma unroll
  for (int j = 0; j < 8; j++) red[g][l * 8 + j] = acc[j];
  __syncthreads();
  float r = 0.f;
#pragma unroll
  for (int gg = 0; gg < 8; gg++) r += red[gg][tid];
  float v = r + bias[tid];
  HC[(size_t)i * 512 + y * 256 + tid] = (bf16)fmaxf(v, 0.f);
}

// ---------------- fused scatter-mean, BOTH branches (gridDim.y=2)
__global__ __launch_bounds__(256) void mean2_k(
    const bf16* __restrict__ Hf,
    const int* __restrict__ offsA, const int* __restrict__ cntA, const int* __restrict__ idsA,
    const int* __restrict__ offsB, const int* __restrict__ cntB, const int* __restrict__ idsB,
    bf16* __restrict__ RC) {
  __shared__ float red[8][256];
  int y = blockIdx.y;
  const int* offs = y ? offsB : offsA;
  const int* cnt  = y ? cntB  : cntA;
  const int* ids  = y ? idsB  : idsA;
  int nb = blockIdx.x;
  int tid = threadIdx.x, g = tid >> 5, l = tid & 31;
  int s0 = offs[nb], c = cnt[nb];
  float acc[8];
#pragma unroll
  for (int j = 0; j < 8; j++) acc[j] = 0.f;
  for (int e = s0 + g; e < s0 + c; e += 8) {
    int t = ids[e];
    bf16x8 v = *(const bf16x8*)(Hf + (size_t)t * DIM + l * 8);
#pragma unroll
    for (int j = 0; j < 8; j++) acc[j] += (float)v[j];
  }
#pragma unroll
  for (int j = 0; j < 8; j++) red[g][l * 8 + j] = acc[j];
  __syncthreads();
  float r = 0.f;
#pragma unroll
  for (int gg = 0; gg < 8; gg++) r += red[gg][tid];
  float denom = (c > 0) ? (float)c : 1.f;
  RC[(size_t)nb * 512 + y * 256 + tid] = (bf16)(r / denom);
}

// ---------------- skinny MFMA GEMM, whole-K A-tile in LDS, barrier-free K-loop.
// A bf16 [M,K] row-major, Wt bf16 [NOUT][K], C bf16 [M,NOUT].
// NOUT=256 -> 4 waves; NOUT=512 -> 8 waves (branch-pair fusion: A staged once).
// A staged via global_load_lds w/ XOR-swizzled source (linear LDS dest);
// B fragments read directly from L2-hot Wt.
template <int K, int NOUT>
__global__ __launch_bounds__(NOUT) void gemm_b_k(
    const bf16* __restrict__ A, const bf16* __restrict__ Wt,
    const float* __restrict__ bias, bf16* __restrict__ C,
    int M, int relu) {
  constexpr int RB = K * 2;                  // bytes per row
  constexpr int RSH = (K == 256) ? 9 : 10;   // log2(RB)
  constexpr int NC = (64 * RB) / 1024;       // 1 KiB staging chunks
  constexpr int NW = NOUT / 64;              // waves
  __shared__ __align__(16) char As[64 * RB];
  int tid = threadIdx.x;
  int wv = tid >> 6, ln = tid & 63;
  int q = ln >> 4, r16 = ln & 15;
  int bm = blockIdx.x * 64;
  const char* Ab = (const char*)(A + (size_t)bm * K);
  for (int c = wv; c < NC; c += NW) {
    int lo = c * 1024;                       // wave-uniform LDS dest
    int t = lo + ln * 16;                    // linear tile byte this lane covers
    int row = t >> RSH;
    int src = t ^ ((row & 7) << 4);          // inverse-swizzle the SOURCE
    __builtin_amdgcn_global_load_lds((gu32*)(Ab + src), (lu32*)(As + lo), 16, 0, 0);
  }
  __syncthreads();                           // only barrier in the kernel body

  const bf16* Bp = Wt + (size_t)(wv * 64 + r16) * K + q * 8;
  f32x4 acc[4][4];
#pragma unroll
  for (int i = 0; i < 4; i++)
#pragma unroll
    for (int j = 0; j < 4; j++) acc[i][j] = f32x4{0.f, 0.f, 0.f, 0.f};

  int abase[4], axor[4];
#pragma unroll
  for (int mi = 0; mi < 4; mi++) {
    int row = mi * 16 + r16;
    abase[mi] = row * RB + q * 16;
    axor[mi] = (row & 7) << 4;
  }
#pragma unroll 2
  for (int k0 = 0; k0 < K; k0 += 32) {
    bf16x8 af[4], bv[4];
#pragma unroll
    for (int mi = 0; mi < 4; mi++)
      af[mi] = *(const bf16x8*)(As + ((abase[mi] + k0 * 2) ^ axor[mi]));
#pragma unroll
    for (int ni = 0; ni < 4; ni++)
      bv[ni] = *(const bf16x8*)(Bp + (size_t)ni * 16 * K + k0);
#pragma unroll
    for (int mi = 0; mi < 4; mi++)
#pragma unroll
      for (int ni = 0; ni < 4; ni++)
        acc[mi][ni] = __builtin_amdgcn_mfma_f32_16x16x32_bf16(af[mi], bv[ni], acc[mi][ni], 0, 0, 0);
  }
#pragma unroll
  for (int ni = 0; ni < 4; ni++) {
    int ng = wv * 64 + ni * 16 + r16;
    float bvv = bias ? bias[ng] : 0.f;
#pragma unroll
    for (int mi = 0; mi < 4; mi++) {
#pragma unroll
      for (int rr = 0; rr < 4; rr++) {
        int mg = bm + mi * 16 + q * 4 + rr;
        if (mg < M) {
          float vv = acc[mi][ni][rr] + bvv;
          if (relu) vv = fmaxf(vv, 0.f);
          C[(size_t)mg * NOUT + ng] = (bf16)vv;
        }
      }
    }
  }
}

// ---------------- GEMM1: A = x fp32 [50000,4652] cvt->bf16, double-buffered As,
// one barrier per K-step, B direct from L2 (WtI1 is 2.4 MB, L2-resident).
#define LDA 40   // LDS row pad (elements) to spread banks

__device__ __forceinline__ void load_x8(const float* __restrict__ Xp, int kg, float* f) {
  if (kg + 8 <= FIN) {
    float4 u0 = *(const float4*)(Xp + kg);
    float4 u1 = *(const float4*)(Xp + kg + 4);
    f[0] = u0.x; f[1] = u0.y; f[2] = u0.z; f[3] = u0.w;
    f[4] = u1.x; f[5] = u1.y; f[6] = u1.z; f[7] = u1.w;
  } else {
#pragma unroll
    for (int j = 0; j < 8; j++) f[j] = (kg + j < FIN) ? Xp[kg + j] : 0.f;
  }
}

__global__ __launch_bounds__(256) void gemm_x_k(
    const float* __restrict__ X, const bf16* __restrict__ Wt,
    const float* __restrict__ bias, bf16* __restrict__ C) {
  __shared__ __align__(16) bf16 As[2][64 * LDA];
  int tid = threadIdx.x;
  int wv = tid >> 6, ln = tid & 63;
  int q = ln >> 4, r16 = ln & 15;
  int bm = blockIdx.x * 64;
  int ar = tid >> 2, acol = (tid & 3) * 8;      // 8 fp32/thread per step
  int arow = bm + ar; if (arow > T_N - 1) arow = T_N - 1;   // X is an input: clamp
  const float* Xp = X + (size_t)arow * FIN;
  const bf16* Bp = Wt + (size_t)(wv * 64 + r16) * KP1 + q * 8;
  f32x4 acc[4][4];
#pragma unroll
  for (int i = 0; i < 4; i++)
#pragma unroll
    for (int j = 0; j < 4; j++) acc[i][j] = f32x4{0.f, 0.f, 0.f, 0.f};

  {                                             // prologue: stage tile 0
    float f0[8];
    load_x8(Xp, acol, f0);
    bf16x8 av;
#pragma unroll
    for (int j = 0; j < 8; j++) av[j] = (bf16)f0[j];
    *(bf16x8*)&As[0][ar * LDA + acol] = av;
  }
  __syncthreads();
  int cur = 0;
  for (int k0 = 0; k0 < KP1; k0 += 32) {
    float fn[8];
    int have = (k0 + 32 < KP1);
    if (have) load_x8(Xp, k0 + 32 + acol, fn);  // issue next-tile loads early
    bf16x8 af[4], bv[4];
#pragma unroll
    for (int mi = 0; mi < 4; mi++)
      af[mi] = *(const bf16x8*)&As[cur][(mi * 16 + r16) * LDA + q * 8];
#pragma unroll
    for (int ni = 0; ni < 4; ni++)
      bv[ni] = *(const bf16x8*)(Bp + (size_t)ni * 16 * KP1 + k0);
#pragma unroll
    for (int mi = 0; mi < 4; mi++)
#pragma unroll
      for (int ni = 0; ni < 4; ni++)
        acc[mi][ni] = __builtin_amdgcn_mfma_f32_16x16x32_bf16(af[mi], bv[ni], acc[mi][ni], 0, 0, 0);
    if (have) {
      bf16x8 av;
#pragma unroll
      for (int j = 0; j < 8; j++) av[j] = (bf16)fn[j];
      *(bf16x8*)&As[cur ^ 1][ar * LDA + acol] = av;   // write the OTHER buffer
    }
    __syncthreads();                             // single barrier per step
    cur ^= 1;
  }
#pragma unroll
  for (int ni = 0; ni < 4; ni++) {
    int ng = wv * 64 + ni * 16 + r16;
    float bv2 = bias[ng];
#pragma unroll
    for (int mi = 0; mi < 4; mi++) {
#pragma unroll
      for (int rr = 0; rr < 4; rr++) {
        int mg = bm + mi * 16 + q * 4 + rr;
        if (mg < T_N) {
          float v = fmaxf(acc[mi][ni][rr] + bv2, 0.f);   // relu
          C[(size_t)mg * DIM + ng] = (bf16)v;
        }
      }
    }
  }
}

// ---------------- head: logits = F1 @ Wfb + bfb; log_softmax. one wave per row
__global__ void final_k(const bf16* __restrict__ F1, const float* __restrict__ Wfb,
                        const float* __restrict__ bfb, float* __restrict__ out) {
  int i = blockIdx.x, l = threadIdx.x;   // 64 threads
  float p[5] = {0.f, 0.f, 0.f, 0.f, 0.f};
  for (int k = l; k < DIM; k += 64) {
    float v = (float)F1[(size_t)i * DIM + k];
#pragma unroll
    for (int c = 0; c < 5; c++) p[c] += v * Wfb[k * 5 + c];
  }
#pragma unroll
  for (int off = 32; off > 0; off >>= 1)
#pragma unroll
    for (int c = 0; c < 5; c++) p[c] += __shfl_down(p[c], off);
  if (l == 0) {
    float z[5], m = -1e30f;
#pragma unroll
    for (int c = 0; c < 5; c++) { z[c] = p[c] + bfb[c]; m = fmaxf(m, z[c]); }
    float s = 0.f;
#pragma unroll
    for (int c = 0; c < 5; c++) s += expf(z[c] - m);
    float ls = m + logf(s);
#pragma unroll
    for (int c = 0; c < 5; c++) out[(size_t)i * 5 + c] = z[c] - ls;
  }
}

extern "C" void kernel_launch(void* const* d_in, const int* in_sizes, int n_in,
                              void* d_out, int out_size, void* d_ws, size_t ws_size,
                              hipStream_t stream) {
  (void)in_sizes; (void)out_size; (void)ws_size;
  if (n_in < 29) return;
  const float* x    = (const float*)d_in[0];
  const int* ei1    = (const int*)d_in[1];
  const int* ei2    = (const int*)d_in[2];
  const int* idx1   = (const int*)d_in[3];
  const int* idx2   = (const int*)d_in[4];
  const float* W_i1 = (const float*)d_in[5];  const float* b_i1 = (const float*)d_in[6];
  const float* W_i2 = (const float*)d_in[7];  const float* b_i2 = (const float*)d_in[8];
  const float* Wc11 = (const float*)d_in[9];  const float* bc11 = (const float*)d_in[10];
  const float* Wc12 = (const float*)d_in[11]; const float* bc12 = (const float*)d_in[12];
  const float* Wc21 = (const float*)d_in[13]; const float* bc21 = (const float*)d_in[14];
  const float* Wc22 = (const float*)d_in[15]; const float* bc22 = (const float*)d_in[16];
  const float* Wm1a = (const float*)d_in[17]; const float* bm1a = (const float*)d_in[18];
  const float* Wm1b = (const float*)d_in[19]; const float* bm1b = (const float*)d_in[20];
  const float* Wm2a = (const float*)d_in[21]; const float* bm2a = (const float*)d_in[22];
  const float* Wm2b = (const float*)d_in[23]; const float* bm2b = (const float*)d_in[24];
  const float* Wfa  = (const float*)d_in[25]; const float* bfa  = (const float*)d_in[26];
  const float* Wfb  = (const float*)d_in[27]; const float* bfb  = (const float*)d_in[28];

  char* base = (char*)d_ws;
  size_t off = 0;
  auto alloc = [&](size_t bytes) -> void* {
    off = (off + 255) & ~(size_t)255;
    void* p = base + off;
    off += bytes;
    return p;
  };

  bf16* WtI1  = (bf16*)alloc((size_t)DIM * KP1 * 2);
  bf16* WtI2  = (bf16*)alloc((size_t)DIM * 256 * 2);
  bf16* WtC1  = (bf16*)alloc((size_t)512 * 256 * 2);   // [512 out][256 K]: C11|C12
  bf16* WtC2  = (bf16*)alloc((size_t)512 * 256 * 2);   // C21|C22
  bf16* WtM1a = (bf16*)alloc((size_t)DIM * 512 * 2);
  bf16* WtM1b = (bf16*)alloc((size_t)DIM * 256 * 2);
  bf16* WtM2a = (bf16*)alloc((size_t)DIM * 512 * 2);
  bf16* WtM2b = (bf16*)alloc((size_t)DIM * 256 * 2);
  bf16* WtFa  = (bf16*)alloc((size_t)DIM * 512 * 2);

  int* cnt1   = (int*)alloc((size_t)T_N * 4);   // contiguous count region (memset)
  int* cnt2   = (int*)alloc((size_t)T_N * 4);
  int* cntN1  = (int*)alloc((size_t)N_N * 4);
  int* cntN2  = (int*)alloc((size_t)N_N * 4);
  int* offs1  = (int*)alloc((size_t)T_N * 4);
  int* curs1  = (int*)alloc((size_t)T_N * 4);
  int* offs2  = (int*)alloc((size_t)T_N * 4);
  int* curs2  = (int*)alloc((size_t)T_N * 4);
  int* offsN1 = (int*)alloc((size_t)N_N * 4);
  int* cursN1 = (int*)alloc((size_t)N_N * 4);
  int* offsN2 = (int*)alloc((size_t)N_N * 4);
  int* cursN2 = (int*)alloc((size_t)N_N * 4);
  float* dinv1 = (float*)alloc((size_t)T_N * 4);
  float* dinv2 = (float*)alloc((size_t)T_N * 4);
  int* sorted1 = (int*)alloc((size_t)E_N * 4);
  int* sorted2 = (int*)alloc((size_t)E_N * 4);
  int* sortedN1 = (int*)alloc((size_t)T_N * 4);
  int* sortedN2 = (int*)alloc((size_t)T_N * 4);
  bf16* SB0 = (bf16*)alloc((size_t)T_N * DIM * 2);   // 25.6 MB
  bf16* SB1 = (bf16*)alloc((size_t)T_N * DIM * 2);   // 25.6 MB
  bf16* P12 = (bf16*)alloc((size_t)T_N * 512 * 2);   // 51.2 MB (pair GEMM out)
  bf16* HC  = (bf16*)alloc((size_t)T_N * 512 * 2);   // 51.2 MB (concat gcn out)
  bf16* RC  = (bf16*)alloc((size_t)N_N * 512 * 2);
  bf16* F1  = (bf16*)alloc((size_t)N_N * DIM * 2);
  float* out = (float*)d_out;

  // zero the count arrays (ws is poisoned before every call)
  hipMemsetAsync(cnt1, 0, (size_t)((char*)cntN2 + (size_t)N_N * 4 - (char*)cnt1), stream);

  // fused weight prep
  PrepDesc pp;
  const float* srcs[11] = {W_i1, W_i2, Wc11, Wc12, Wc21, Wc22, Wm1a, Wm1b, Wm2a, Wm2b, Wfa};
  bf16* dsts[11] = {WtI1, WtI2, WtC1, WtC1 + (size_t)256 * 256, WtC2, WtC2 + (size_t)256 * 256,
                    WtM1a, WtM1b, WtM2a, WtM2b, WtFa};
  int Ks[11] = {FIN, 256, 256, 256, 256, 256, 512, 256, 512, 256, 512};
  int Kp[11] = {KP1, 256, 256, 256, 256, 256, 512, 256, 512, 256, 512};
  int acc = 0;
  for (int e = 0; e < 11; e++) {
    pp.src[e] = srcs[e]; pp.dst[e] = dsts[e]; pp.K[e] = Ks[e];
    pp.off[e] = acc; acc += Kp[e];
  }
  pp.off[11] = acc;    // 8000
  prep_all_k<<<acc, 256, 0, stream>>>(pp);

  // graph preprocessing: fused hist -> 4-block scan (emits dinv) -> fused scatter
  const int GP = (2 * E_N + 2 * T_N + 255) / 256;
  hist_all_k<<<GP, 256, 0, stream>>>(ei1, ei2, idx1, idx2, cnt1, cnt2, cntN1, cntN2);
  scan4_k<<<4, 1024, 0, stream>>>(cnt1, cnt2, cntN1, cntN2,
                                  offs1, offs2, offsN1, offsN2,
                                  curs1, curs2, cursN1, cursN2,
                                  dinv1, dinv2);
  scatter_all_k<<<GP, 256, 0, stream>>>(ei1, ei2, idx1, idx2,
                                        curs1, curs2, cursN1, cursN2,
                                        sorted1, sorted2, sortedN1, sortedN2);

  // network
  const int GM = (T_N + 63) / 64;    // 782
  const int GMn = (N_N + 63) / 64;   // 79
  gemm_x_k<<<GM, 256, 0, stream>>>(x, WtI1, b_i1, SB0);                          // A1=relu(x@Wi1+b)
  gemm_b_k<256, 256><<<GM, 256, 0, stream>>>(SB0, WtI2, b_i2, SB1, T_N, 0);      // H=A1@Wi2+b
  gemm_b_k<256, 512><<<GM, 512, 0, stream>>>(SB1, WtC1, nullptr, P12, T_N, 0);   // P12=H@[Wc11|Wc12]
  gcn2_k<<<dim3(T_N, 2), 256, 0, stream>>>(P12,
      offs1, cnt1, sorted1, dinv1, bc11,
      offs2, cnt2, sorted2, dinv2, bc12, HC);
  gemm_b_k<512, 256><<<GM, 256, 0, stream>>>(HC, WtM1a, bm1a, SB0, T_N, 1);      // A2=relu(HC@Wm1a+b)
  gemm_b_k<256, 256><<<GM, 256, 0, stream>>>(SB0, WtM1b, bm1b, SB1, T_N, 0);     // H'=A2@Wm1b+b
  gemm_b_k<256, 512><<<GM, 512, 0, stream>>>(SB1, WtC2, nullptr, P12, T_N, 0);   // P12=H'@[Wc21|Wc22]
  gcn2_k<<<dim3(T_N, 2), 256, 0, stream>>>(P12,
      offs1, cnt1, sorted1, dinv1, bc21,
      offs2, cnt2, sorted2, dinv2, bc22, HC);
  gemm_b_k<512, 256><<<GM, 256, 0, stream>>>(HC, WtM2a, bm2a, SB0, T_N, 1);      // A3=relu(HC@Wm2a+b)
  gemm_b_k<256, 256><<<GM, 256, 0, stream>>>(SB0, WtM2b, bm2b, SB1, T_N, 0);     // Hf=A3@Wm2b+b
  mean2_k<<<dim3(N_N, 2), 256, 0, stream>>>(SB1,
      offsN1, cntN1, sortedN1, offsN2, cntN2, sortedN2, RC);                     // r1|r2
  gemm_b_k<512, 256><<<GMn, 256, 0, stream>>>(RC, WtFa, bfa, F1, N_N, 1);        // relu(RC@Wfa+b)
  final_k<<<N_N, 64, 0, stream>>>(F1, Wfb, bfb, out);                            // logits + log_softmax
}